// Round 1
// baseline (334.214 us; speedup 1.0000x reference)
//
#include <hip/hip_runtime.h>
#include <hip/hip_bf16.h>
#include <math.h>

typedef __bf16 bf16;
typedef __bf16 bf16x8 __attribute__((ext_vector_type(8)));
typedef float f32x4 __attribute__((ext_vector_type(4)));

#define MFMA16(a, b, c) __builtin_amdgcn_mfma_f32_16x16x32_bf16(a, b, c, 0, 0, 0)

constexpr int D_MODEL = 1024;
constexpr int N_QKV   = 3072;
constexpr int BATCH   = 2;
constexpr int SEQ     = 2048;
constexpr int NH      = 16;
constexpr int DH      = 64;
constexpr int M_TOT   = BATCH * SEQ;   // 4096

// ---------------------------------------------------------------------------
// Kernel 1: qkv = X @ W_qkv  (fp32 inputs, bf16 MFMA), epilogue de-interleaves
// q/k/v (interleaved layout n = h*192 + d*3 + which) into [b,h,s,d] bf16 bufs.
// 64x64 tile / wg, 4 waves, each wave owns 16 rows x 64 cols.
// ---------------------------------------------------------------------------
__global__ __launch_bounds__(256) void qkv_gemm_kernel(
    const float* __restrict__ X, const float* __restrict__ W,
    bf16* __restrict__ qb, bf16* __restrict__ kb, bf16* __restrict__ vb)
{
    __shared__ bf16 As[64][72];   // [m][k], +8 pad breaks b128 bank conflicts
    __shared__ bf16 Bt[64][72];   // [n][k] transposed

    const int tid  = threadIdx.x;
    const int wave = tid >> 6;
    const int lane = tid & 63;
    const int quad = lane >> 4;
    const int l16  = lane & 15;
    const int m0   = blockIdx.x * 64;
    const int n0   = blockIdx.y * 64;

    const int ar = tid >> 2;          // staging row 0..63
    const int ac = (tid & 3) * 16;    // staging col base {0,16,32,48}

    f32x4 acc[4] = {{0.f,0.f,0.f,0.f},{0.f,0.f,0.f,0.f},
                    {0.f,0.f,0.f,0.f},{0.f,0.f,0.f,0.f}};

    for (int kb0 = 0; kb0 < D_MODEL; kb0 += 64) {
        // --- stage A tile (fp32 -> bf16) ---
        {
            const float* src = X + (size_t)(m0 + ar) * D_MODEL + kb0 + ac;
            f32x4 v0 = *(const f32x4*)(src + 0);
            f32x4 v1 = *(const f32x4*)(src + 4);
            f32x4 v2 = *(const f32x4*)(src + 8);
            f32x4 v3 = *(const f32x4*)(src + 12);
            bf16x8 w0, w1;
            #pragma unroll
            for (int j = 0; j < 4; j++) {
                w0[j]     = (bf16)v0[j];
                w0[j + 4] = (bf16)v1[j];
                w1[j]     = (bf16)v2[j];
                w1[j + 4] = (bf16)v3[j];
            }
            *(bf16x8*)&As[ar][ac]     = w0;
            *(bf16x8*)&As[ar][ac + 8] = w1;
        }
        // --- stage B tile transposed (fp32 -> bf16) ---
        {
            const float* src = W + (size_t)(kb0 + ar) * N_QKV + n0 + ac;
            f32x4 b0 = *(const f32x4*)(src + 0);
            f32x4 b1 = *(const f32x4*)(src + 4);
            f32x4 b2 = *(const f32x4*)(src + 8);
            f32x4 b3 = *(const f32x4*)(src + 12);
            #pragma unroll
            for (int j = 0; j < 4; j++) {
                Bt[ac + j][ar]      = (bf16)b0[j];
                Bt[ac + 4 + j][ar]  = (bf16)b1[j];
                Bt[ac + 8 + j][ar]  = (bf16)b2[j];
                Bt[ac + 12 + j][ar] = (bf16)b3[j];
            }
        }
        __syncthreads();

        #pragma unroll
        for (int ks = 0; ks < 2; ks++) {
            bf16x8 af = *(const bf16x8*)&As[wave * 16 + l16][ks * 32 + quad * 8];
            #pragma unroll
            for (int t = 0; t < 4; t++) {
                bf16x8 bfrag = *(const bf16x8*)&Bt[t * 16 + l16][ks * 32 + quad * 8];
                acc[t] = MFMA16(af, bfrag, acc[t]);
            }
        }
        __syncthreads();
    }

    // --- epilogue: scatter to q/k/v [b][h][s][d] bf16 ---
    const int row0 = m0 + wave * 16 + quad * 4;
    #pragma unroll
    for (int t = 0; t < 4; t++) {
        int n     = n0 + t * 16 + l16;
        int h     = n / 192;
        int rem   = n - h * 192;
        int d     = rem / 3;
        int which = rem - d * 3;
        bf16* dst = (which == 0) ? qb : ((which == 1) ? kb : vb);
        #pragma unroll
        for (int i = 0; i < 4; i++) {
            int m    = row0 + i;
            int b    = m >> 11;            // m / SEQ
            int sidx = m & (SEQ - 1);
            dst[((size_t)(b * NH + h) * SEQ + sidx) * DH + d] = (bf16)acc[t][i];
        }
    }
}

// ---------------------------------------------------------------------------
// Kernel 2: flash attention. One wg per (b*h, q-tile of 64). 4 waves, each
// owns 16 q rows. K-tiles of 64 keys; online softmax with per-lane partial l.
// ---------------------------------------------------------------------------
__global__ __launch_bounds__(256) void attn_kernel(
    const bf16* __restrict__ qb, const bf16* __restrict__ kb,
    const bf16* __restrict__ vb, bf16* __restrict__ ob)
{
    __shared__ bf16 Ks[64][72];      // [key][d]
    __shared__ bf16 Vt[64][72];      // [d][key] (transposed)
    __shared__ bf16 Ps[4][16][72];   // per-wave P tile [q_local][key]

    const int tid  = threadIdx.x;
    const int wave = tid >> 6;
    const int lane = tid & 63;
    const int quad = lane >> 4;
    const int l16  = lane & 15;
    const int bh   = blockIdx.x;          // 0..31
    const int q0   = blockIdx.y * 64;
    const size_t base = (size_t)bh * SEQ * DH;

    // Q fragments (A-operand layout), rows wave*16 + l16
    const size_t qoff = base + (size_t)(q0 + wave * 16 + l16) * DH + quad * 8;
    bf16x8 qf0 = *(const bf16x8*)(qb + qoff);
    bf16x8 qf1 = *(const bf16x8*)(qb + qoff + 32);

    float m_i[4], l_i[4];
    f32x4 o_acc[4] = {{0.f,0.f,0.f,0.f},{0.f,0.f,0.f,0.f},
                      {0.f,0.f,0.f,0.f},{0.f,0.f,0.f,0.f}};
    #pragma unroll
    for (int i = 0; i < 4; i++) { m_i[i] = -INFINITY; l_i[i] = 0.f; }

    const int sr = tid >> 2;          // staging row 0..63
    const int sc = (tid & 3) * 16;    // staging col base

    for (int k0 = 0; k0 < SEQ; k0 += 64) {
        __syncthreads();   // previous tile's LDS reads complete
        // --- stage K tile + V tile (V transposed) ---
        {
            const bf16* ksrc = kb + base + (size_t)(k0 + sr) * DH + sc;
            *(bf16x8*)&Ks[sr][sc]     = *(const bf16x8*)(ksrc);
            *(bf16x8*)&Ks[sr][sc + 8] = *(const bf16x8*)(ksrc + 8);
            const bf16* vsrc = vb + base + (size_t)(k0 + sr) * DH + sc;
            bf16x8 v0 = *(const bf16x8*)(vsrc);
            bf16x8 v1 = *(const bf16x8*)(vsrc + 8);
            #pragma unroll
            for (int j = 0; j < 8; j++) {
                Vt[sc + j][sr]     = v0[j];
                Vt[sc + 8 + j][sr] = v1[j];
            }
        }
        __syncthreads();

        // --- S = Q K^T (rows quad*4+i, cols t*16+l16) ---
        f32x4 sacc[4] = {{0.f,0.f,0.f,0.f},{0.f,0.f,0.f,0.f},
                         {0.f,0.f,0.f,0.f},{0.f,0.f,0.f,0.f}};
        #pragma unroll
        for (int t = 0; t < 4; t++) {
            bf16x8 kf0 = *(const bf16x8*)&Ks[t * 16 + l16][quad * 8];
            sacc[t] = MFMA16(qf0, kf0, sacc[t]);
            bf16x8 kf1 = *(const bf16x8*)&Ks[t * 16 + l16][32 + quad * 8];
            sacc[t] = MFMA16(qf1, kf1, sacc[t]);
        }

        float sv[4][4];
        #pragma unroll
        for (int t = 0; t < 4; t++)
            #pragma unroll
            for (int i = 0; i < 4; i++)
                sv[t][i] = sacc[t][i] * 0.125f;   // 1/sqrt(64)

        // --- online softmax (row r = quad*4+i spans 16 lanes of this quad) ---
        #pragma unroll
        for (int i = 0; i < 4; i++) {
            float rm = fmaxf(fmaxf(sv[0][i], sv[1][i]), fmaxf(sv[2][i], sv[3][i]));
            rm = fmaxf(rm, __shfl_xor(rm, 1));
            rm = fmaxf(rm, __shfl_xor(rm, 2));
            rm = fmaxf(rm, __shfl_xor(rm, 4));
            rm = fmaxf(rm, __shfl_xor(rm, 8));
            float mn    = fmaxf(m_i[i], rm);
            float alpha = __expf(m_i[i] - mn);
            m_i[i] = mn;
            float psum = 0.f;
            #pragma unroll
            for (int t = 0; t < 4; t++) {
                float p = __expf(sv[t][i] - mn);
                psum += p;
                Ps[wave][quad * 4 + i][t * 16 + l16] = (bf16)p;
            }
            l_i[i] = l_i[i] * alpha + psum;   // lane-partial; reduced at end
            #pragma unroll
            for (int t = 0; t < 4; t++) o_acc[t][i] *= alpha;
        }
        __syncthreads();   // P visible for A-layout reads

        // --- O += P @ V ---
        #pragma unroll
        for (int ks = 0; ks < 2; ks++) {
            bf16x8 pf = *(const bf16x8*)&Ps[wave][l16][ks * 32 + quad * 8];
            #pragma unroll
            for (int t = 0; t < 4; t++) {
                bf16x8 vf = *(const bf16x8*)&Vt[t * 16 + l16][ks * 32 + quad * 8];
                o_acc[t] = MFMA16(pf, vf, o_acc[t]);
            }
        }
    }

    // --- finalize: reduce lane-partial l across the quad's 16 lanes ---
    #pragma unroll
    for (int i = 0; i < 4; i++) {
        float s = l_i[i];
        s += __shfl_xor(s, 1);
        s += __shfl_xor(s, 2);
        s += __shfl_xor(s, 4);
        s += __shfl_xor(s, 8);
        l_i[i] = 1.0f / s;
    }

    const int b = bh >> 4, h = bh & 15;
    #pragma unroll
    for (int t = 0; t < 4; t++) {
        #pragma unroll
        for (int i = 0; i < 4; i++) {
            int q = q0 + wave * 16 + quad * 4 + i;
            ob[((size_t)(b * SEQ + q) * NH + h) * DH + t * 16 + l16] =
                (bf16)(o_acc[t][i] * l_i[i]);
        }
    }
}

// ---------------------------------------------------------------------------
// Kernel 3: out = attn @ W_out  (bf16 A, fp32 W converted in staging, fp32 out)
// ---------------------------------------------------------------------------
__global__ __launch_bounds__(256) void out_gemm_kernel(
    const bf16* __restrict__ A, const float* __restrict__ W,
    float* __restrict__ out)
{
    __shared__ bf16 As[64][72];
    __shared__ bf16 Bt[64][72];

    const int tid  = threadIdx.x;
    const int wave = tid >> 6;
    const int lane = tid & 63;
    const int quad = lane >> 4;
    const int l16  = lane & 15;
    const int m0   = blockIdx.x * 64;
    const int n0   = blockIdx.y * 64;

    const int ar = tid >> 2;
    const int ac = (tid & 3) * 16;

    f32x4 acc[4] = {{0.f,0.f,0.f,0.f},{0.f,0.f,0.f,0.f},
                    {0.f,0.f,0.f,0.f},{0.f,0.f,0.f,0.f}};

    for (int kb0 = 0; kb0 < D_MODEL; kb0 += 64) {
        {
            const bf16* src = A + (size_t)(m0 + ar) * D_MODEL + kb0 + ac;
            *(bf16x8*)&As[ar][ac]     = *(const bf16x8*)(src);
            *(bf16x8*)&As[ar][ac + 8] = *(const bf16x8*)(src + 8);
        }
        {
            const float* src = W + (size_t)(kb0 + ar) * D_MODEL + n0 + ac;
            f32x4 b0 = *(const f32x4*)(src + 0);
            f32x4 b1 = *(const f32x4*)(src + 4);
            f32x4 b2 = *(const f32x4*)(src + 8);
            f32x4 b3 = *(const f32x4*)(src + 12);
            #pragma unroll
            for (int j = 0; j < 4; j++) {
                Bt[ac + j][ar]      = (bf16)b0[j];
                Bt[ac + 4 + j][ar]  = (bf16)b1[j];
                Bt[ac + 8 + j][ar]  = (bf16)b2[j];
                Bt[ac + 12 + j][ar] = (bf16)b3[j];
            }
        }
        __syncthreads();

        #pragma unroll
        for (int ks = 0; ks < 2; ks++) {
            bf16x8 af = *(const bf16x8*)&As[wave * 16 + l16][ks * 32 + quad * 8];
            #pragma unroll
            for (int t = 0; t < 4; t++) {
                bf16x8 bfrag = *(const bf16x8*)&Bt[t * 16 + l16][ks * 32 + quad * 8];
                acc[t] = MFMA16(af, bfrag, acc[t]);
            }
        }
        __syncthreads();
    }

    const int row0 = m0 + wave * 16 + quad * 4;
    #pragma unroll
    for (int t = 0; t < 4; t++) {
        int n = n0 + t * 16 + l16;
        #pragma unroll
        for (int i = 0; i < 4; i++) {
            out[(size_t)(row0 + i) * D_MODEL + n] = acc[t][i];
        }
    }
}

// ---------------------------------------------------------------------------
extern "C" void kernel_launch(void* const* d_in, const int* in_sizes, int n_in,
                              void* d_out, int out_size, void* d_ws, size_t ws_size,
                              hipStream_t stream)
{
    const float* X    = (const float*)d_in[0];
    const float* Wqkv = (const float*)d_in[1];
    const float* Wout = (const float*)d_in[2];
    float* out        = (float*)d_out;

    const size_t n_elem = (size_t)M_TOT * D_MODEL;   // 4096*1024
    bf16* qb    = (bf16*)d_ws;
    bf16* kb    = qb + n_elem;
    bf16* vb    = kb + n_elem;
    bf16* attnb = vb + n_elem;   // total 4 * 8 MB = 33.5 MB of ws

    qkv_gemm_kernel<<<dim3(M_TOT / 64, N_QKV / 64), 256, 0, stream>>>(X, Wqkv, qb, kb, vb);
    attn_kernel<<<dim3(BATCH * NH, SEQ / 64), 256, 0, stream>>>(qb, kb, vb, attnb);
    out_gemm_kernel<<<dim3(M_TOT / 64, D_MODEL / 64), 256, 0, stream>>>(attnb, Wout, out);
}

// Round 2
// 254.052 us; speedup vs baseline: 1.3155x; 1.3155x over previous
//
#include <hip/hip_runtime.h>
#include <hip/hip_bf16.h>
#include <math.h>

typedef __bf16 bf16;
typedef __bf16 bf16x4 __attribute__((ext_vector_type(4)));
typedef __bf16 bf16x8 __attribute__((ext_vector_type(8)));
typedef float f32x4 __attribute__((ext_vector_type(4)));

#define MFMA16(a, b, c) __builtin_amdgcn_mfma_f32_16x16x32_bf16(a, b, c, 0, 0, 0)

constexpr int D_MODEL = 1024;
constexpr int N_QKV   = 3072;
constexpr int BATCH   = 2;
constexpr int SEQ     = 2048;
constexpr int NH      = 16;
constexpr int DH      = 64;
constexpr int M_TOT   = BATCH * SEQ;   // 4096

// ---------------------------------------------------------------------------
// Pre-pass: W fp32 [K][N]  ->  bf16 [N][K] (transpose + convert), 64x64 tiles.
// One-time ~25 MB of traffic; runs once per launch.
// ---------------------------------------------------------------------------
__global__ __launch_bounds__(256) void transpose_cvt_kernel(
    const float* __restrict__ in, bf16* __restrict__ out, int K, int N)
{
    __shared__ bf16 T[64][72];
    const int tid = threadIdx.x;
    const int r   = tid >> 2;          // 0..63
    const int c4  = (tid & 3) * 16;    // {0,16,32,48}
    const int n0  = blockIdx.x * 64;
    const int k0  = blockIdx.y * 64;

    const float* src = in + (size_t)(k0 + r) * N + n0 + c4;
    f32x4 v0 = *(const f32x4*)(src + 0);
    f32x4 v1 = *(const f32x4*)(src + 4);
    f32x4 v2 = *(const f32x4*)(src + 8);
    f32x4 v3 = *(const f32x4*)(src + 12);
    #pragma unroll
    for (int j = 0; j < 4; j++) {
        T[c4 + j][r]      = (bf16)v0[j];
        T[c4 + 4 + j][r]  = (bf16)v1[j];
        T[c4 + 8 + j][r]  = (bf16)v2[j];
        T[c4 + 12 + j][r] = (bf16)v3[j];
    }
    __syncthreads();
    bf16* dst = out + (size_t)(n0 + r) * K + k0 + c4;
    *(bf16x8*)(dst)     = *(const bf16x8*)&T[r][c4];
    *(bf16x8*)(dst + 8) = *(const bf16x8*)&T[r][c4 + 8];
}

// ---------------------------------------------------------------------------
// Kernel 1: qkv = X @ W_qkv.  A: fp32->bf16 staged; B: pre-transposed bf16.
// Epilogue de-interleaves q/k/v (n = h*192 + d*3 + which):
//   q,k -> [b,h,s,d];  v -> [b,h,d,s] (transposed, free here, saves attn LDS
//   transpose).
// ---------------------------------------------------------------------------
__global__ __launch_bounds__(256) void qkv_gemm_kernel(
    const float* __restrict__ X, const bf16* __restrict__ Wt,
    bf16* __restrict__ qb, bf16* __restrict__ kb, bf16* __restrict__ vb)
{
    __shared__ bf16 As[64][72];
    __shared__ bf16 Bt[64][72];

    const int tid  = threadIdx.x;
    const int wave = tid >> 6;
    const int lane = tid & 63;
    const int quad = lane >> 4;
    const int l16  = lane & 15;
    const int m0   = blockIdx.x * 64;
    const int n0   = blockIdx.y * 64;

    const int ar = tid >> 2;
    const int ac = (tid & 3) * 16;

    f32x4 acc[4] = {{0.f,0.f,0.f,0.f},{0.f,0.f,0.f,0.f},
                    {0.f,0.f,0.f,0.f},{0.f,0.f,0.f,0.f}};

    for (int kb0 = 0; kb0 < D_MODEL; kb0 += 64) {
        {   // A tile: fp32 -> bf16
            const float* src = X + (size_t)(m0 + ar) * D_MODEL + kb0 + ac;
            f32x4 v0 = *(const f32x4*)(src + 0);
            f32x4 v1 = *(const f32x4*)(src + 4);
            f32x4 v2 = *(const f32x4*)(src + 8);
            f32x4 v3 = *(const f32x4*)(src + 12);
            bf16x8 w0, w1;
            #pragma unroll
            for (int j = 0; j < 4; j++) {
                w0[j] = (bf16)v0[j]; w0[j + 4] = (bf16)v1[j];
                w1[j] = (bf16)v2[j]; w1[j + 4] = (bf16)v3[j];
            }
            *(bf16x8*)&As[ar][ac]     = w0;
            *(bf16x8*)&As[ar][ac + 8] = w1;
        }
        {   // B tile: already bf16 [N][K]
            const bf16* src = Wt + (size_t)(n0 + ar) * D_MODEL + kb0 + ac;
            *(bf16x8*)&Bt[ar][ac]     = *(const bf16x8*)(src);
            *(bf16x8*)&Bt[ar][ac + 8] = *(const bf16x8*)(src + 8);
        }
        __syncthreads();

        #pragma unroll
        for (int ks = 0; ks < 2; ks++) {
            bf16x8 af = *(const bf16x8*)&As[wave * 16 + l16][ks * 32 + quad * 8];
            #pragma unroll
            for (int t = 0; t < 4; t++) {
                bf16x8 bfrag = *(const bf16x8*)&Bt[t * 16 + l16][ks * 32 + quad * 8];
                acc[t] = MFMA16(af, bfrag, acc[t]);
            }
        }
        __syncthreads();
    }

    const int row0 = m0 + wave * 16 + quad * 4;
    #pragma unroll
    for (int t = 0; t < 4; t++) {
        int n     = n0 + t * 16 + l16;
        int h     = n / 192;
        int rem   = n - h * 192;
        int d     = rem / 3;
        int which = rem - d * 3;
        #pragma unroll
        for (int i = 0; i < 4; i++) {
            int m    = row0 + i;
            int b    = m >> 11;
            int sidx = m & (SEQ - 1);
            size_t bh = (size_t)(b * NH + h);
            if (which == 0)
                qb[(bh * SEQ + sidx) * DH + d] = (bf16)acc[t][i];
            else if (which == 1)
                kb[(bh * SEQ + sidx) * DH + d] = (bf16)acc[t][i];
            else
                vb[(bh * DH + d) * SEQ + sidx] = (bf16)acc[t][i];  // transposed
        }
    }
}

// ---------------------------------------------------------------------------
// Kernel 2: flash attention, S^T formulation.
// One wg per (b*h, 64-q tile); 4 waves; wave owns 16 q rows (q local = l16).
// S^T = K Q^T via MFMA(kf, qf): lane holds P[q=l16][key=t*16+quad*4+i] ->
// row-max needs 2 cross-quad shuffles, Ps written as bf16x4.
// V staged from pre-transposed [b,h,d,s] with b128 (no LDS transpose).
// ---------------------------------------------------------------------------
__global__ __launch_bounds__(256) void attn_kernel(
    const bf16* __restrict__ qb, const bf16* __restrict__ kb,
    const bf16* __restrict__ vb, bf16* __restrict__ ob)
{
    __shared__ bf16 Ks[64][72];      // [key][d]
    __shared__ bf16 Vt[64][72];      // [d][key]
    __shared__ bf16 Ps[4][16][72];   // per-wave [q_local=l16][key]

    const int tid  = threadIdx.x;
    const int wave = tid >> 6;
    const int lane = tid & 63;
    const int quad = lane >> 4;
    const int l16  = lane & 15;
    const int bh   = blockIdx.x;
    const int q0   = blockIdx.y * 64;
    const size_t base = (size_t)bh * SEQ * DH;

    // Q fragments, scale 1/sqrt(64) folded in (exact: power of 2)
    const size_t qoff = base + (size_t)(q0 + wave * 16 + l16) * DH + quad * 8;
    bf16x8 qf0 = *(const bf16x8*)(qb + qoff);
    bf16x8 qf1 = *(const bf16x8*)(qb + qoff + 32);
    #pragma unroll
    for (int j = 0; j < 8; j++) {
        qf0[j] = (bf16)((float)qf0[j] * 0.125f);
        qf1[j] = (bf16)((float)qf1[j] * 0.125f);
    }

    float m_i = -INFINITY;   // per q-row (l16), uniform across quads
    float l_i = 0.f;         // per-lane partial (this quad's keys)
    f32x4 o_acc[4] = {{0.f,0.f,0.f,0.f},{0.f,0.f,0.f,0.f},
                      {0.f,0.f,0.f,0.f},{0.f,0.f,0.f,0.f}};

    const int sr = tid >> 2;
    const int sc = (tid & 3) * 16;

    for (int k0 = 0; k0 < SEQ; k0 += 64) {
        __syncthreads();
        {   // stage K [key][d] and V [d][key] — both straight b128 copies
            const bf16* ksrc = kb + base + (size_t)(k0 + sr) * DH + sc;
            *(bf16x8*)&Ks[sr][sc]     = *(const bf16x8*)(ksrc);
            *(bf16x8*)&Ks[sr][sc + 8] = *(const bf16x8*)(ksrc + 8);
            const bf16* vsrc = vb + base + (size_t)sr * SEQ + k0 + sc;
            *(bf16x8*)&Vt[sr][sc]     = *(const bf16x8*)(vsrc);
            *(bf16x8*)&Vt[sr][sc + 8] = *(const bf16x8*)(vsrc + 8);
        }
        __syncthreads();

        // --- S^T = K Q^T: rows = keys (quad*4+i in tile t), cols = q (l16) ---
        f32x4 sacc[4] = {{0.f,0.f,0.f,0.f},{0.f,0.f,0.f,0.f},
                         {0.f,0.f,0.f,0.f},{0.f,0.f,0.f,0.f}};
        #pragma unroll
        for (int t = 0; t < 4; t++) {
            bf16x8 kf0 = *(const bf16x8*)&Ks[t * 16 + l16][quad * 8];
            sacc[t] = MFMA16(kf0, qf0, sacc[t]);
            bf16x8 kf1 = *(const bf16x8*)&Ks[t * 16 + l16][32 + quad * 8];
            sacc[t] = MFMA16(kf1, qf1, sacc[t]);
        }

        // --- online softmax: lane owns q=l16, keys {t*16+quad*4+i} ---
        float lm = sacc[0][0];
        #pragma unroll
        for (int t = 0; t < 4; t++)
            #pragma unroll
            for (int i = 0; i < 4; i++) lm = fmaxf(lm, sacc[t][i]);
        lm = fmaxf(lm, __shfl_xor(lm, 16));
        lm = fmaxf(lm, __shfl_xor(lm, 32));
        float mn    = fmaxf(m_i, lm);
        float alpha = __expf(m_i - mn);
        m_i = mn;

        float psum = 0.f;
        #pragma unroll
        for (int t = 0; t < 4; t++) {
            bf16x4 pv;
            #pragma unroll
            for (int i = 0; i < 4; i++) {
                float p = __expf(sacc[t][i] - mn);
                psum += p;
                pv[i] = (bf16)p;
            }
            *(bf16x4*)&Ps[wave][l16][t * 16 + quad * 4] = pv;
        }
        l_i = l_i * alpha + psum;

        // rescale O (C-layout rows = q local = quad*4+i)
        float alpha_c[4];
        #pragma unroll
        for (int i = 0; i < 4; i++) alpha_c[i] = __shfl(alpha, quad * 4 + i);
        #pragma unroll
        for (int t = 0; t < 4; t++)
            #pragma unroll
            for (int i = 0; i < 4; i++) o_acc[t][i] *= alpha_c[i];

        // --- O += P V  (Ps is per-wave: no barrier, lgkmcnt ordering only) ---
        #pragma unroll
        for (int ks = 0; ks < 2; ks++) {
            bf16x8 pf = *(const bf16x8*)&Ps[wave][l16][ks * 32 + quad * 8];
            #pragma unroll
            for (int t = 0; t < 4; t++) {
                bf16x8 vf = *(const bf16x8*)&Vt[t * 16 + l16][ks * 32 + quad * 8];
                o_acc[t] = MFMA16(pf, vf, o_acc[t]);
            }
        }
    }

    // --- finalize l: reduce quad partials, invert, broadcast to C-layout ---
    l_i += __shfl_xor(l_i, 16);
    l_i += __shfl_xor(l_i, 32);
    float linv = 1.0f / l_i;
    float linv_c[4];
    #pragma unroll
    for (int i = 0; i < 4; i++) linv_c[i] = __shfl(linv, quad * 4 + i);

    const int b = bh >> 4, h = bh & 15;
    #pragma unroll
    for (int t = 0; t < 4; t++) {
        #pragma unroll
        for (int i = 0; i < 4; i++) {
            int q = q0 + wave * 16 + quad * 4 + i;
            ob[((size_t)(b * SEQ + q) * NH + h) * DH + t * 16 + l16] =
                (bf16)(o_acc[t][i] * linv_c[i]);
        }
    }
}

// ---------------------------------------------------------------------------
// Kernel 3: out = attn @ W_out.  A bf16, B pre-transposed bf16, fp32 out.
// ---------------------------------------------------------------------------
__global__ __launch_bounds__(256) void out_gemm_kernel(
    const bf16* __restrict__ A, const bf16* __restrict__ Wt,
    float* __restrict__ out)
{
    __shared__ bf16 As[64][72];
    __shared__ bf16 Bt[64][72];

    const int tid  = threadIdx.x;
    const int wave = tid >> 6;
    const int lane = tid & 63;
    const int quad = lane >> 4;
    const int l16  = lane & 15;
    const int m0   = blockIdx.x * 64;
    const int n0   = blockIdx.y * 64;

    const int ar = tid >> 2;
    const int ac = (tid & 3) * 16;

    f32x4 acc[4] = {{0.f,0.f,0.f,0.f},{0.f,0.f,0.f,0.f},
                    {0.f,0.f,0.f,0.f},{0.f,0.f,0.f,0.f}};

    for (int kb0 = 0; kb0 < D_MODEL; kb0 += 64) {
        {
            const bf16* src = A + (size_t)(m0 + ar) * D_MODEL + kb0 + ac;
            *(bf16x8*)&As[ar][ac]     = *(const bf16x8*)(src);
            *(bf16x8*)&As[ar][ac + 8] = *(const bf16x8*)(src + 8);
        }
        {
            const bf16* src = Wt + (size_t)(n0 + ar) * D_MODEL + kb0 + ac;
            *(bf16x8*)&Bt[ar][ac]     = *(const bf16x8*)(src);
            *(bf16x8*)&Bt[ar][ac + 8] = *(const bf16x8*)(src + 8);
        }
        __syncthreads();

        #pragma unroll
        for (int ks = 0; ks < 2; ks++) {
            bf16x8 af = *(const bf16x8*)&As[wave * 16 + l16][ks * 32 + quad * 8];
            #pragma unroll
            for (int t = 0; t < 4; t++) {
                bf16x8 bfrag = *(const bf16x8*)&Bt[t * 16 + l16][ks * 32 + quad * 8];
                acc[t] = MFMA16(af, bfrag, acc[t]);
            }
        }
        __syncthreads();
    }

    const int row0 = m0 + wave * 16 + quad * 4;
    #pragma unroll
    for (int t = 0; t < 4; t++) {
        int n = n0 + t * 16 + l16;
        #pragma unroll
        for (int i = 0; i < 4; i++) {
            out[(size_t)(row0 + i) * D_MODEL + n] = acc[t][i];
        }
    }
}

// ---------------------------------------------------------------------------
extern "C" void kernel_launch(void* const* d_in, const int* in_sizes, int n_in,
                              void* d_out, int out_size, void* d_ws, size_t ws_size,
                              hipStream_t stream)
{
    const float* X    = (const float*)d_in[0];
    const float* Wqkv = (const float*)d_in[1];
    const float* Wout = (const float*)d_in[2];
    float* out        = (float*)d_out;

    const size_t n_elem = (size_t)M_TOT * D_MODEL;       // 4096*1024
    bf16* qb      = (bf16*)d_ws;
    bf16* kb      = qb + n_elem;
    bf16* vb      = kb + n_elem;
    bf16* attnb   = vb + n_elem;
    bf16* wqkv_t  = attnb + n_elem;                      // 3072*1024
    bf16* wout_t  = wqkv_t + (size_t)N_QKV * D_MODEL;    // 1024*1024
    // total ws: (4*4M + 3M + 1M) * 2B = 41.9 MB

    transpose_cvt_kernel<<<dim3(N_QKV / 64, D_MODEL / 64), 256, 0, stream>>>(
        Wqkv, wqkv_t, D_MODEL, N_QKV);
    transpose_cvt_kernel<<<dim3(D_MODEL / 64, D_MODEL / 64), 256, 0, stream>>>(
        Wout, wout_t, D_MODEL, D_MODEL);

    qkv_gemm_kernel<<<dim3(M_TOT / 64, N_QKV / 64), 256, 0, stream>>>(
        X, wqkv_t, qb, kb, vb);
    attn_kernel<<<dim3(BATCH * NH, SEQ / 64), 256, 0, stream>>>(qb, kb, vb, attnb);
    out_gemm_kernel<<<dim3(M_TOT / 64, D_MODEL / 64), 256, 0, stream>>>(
        attnb, wout_t, out);
}